// Round 12
// baseline (338.902 us; speedup 1.0000x reference)
//
#include <hip/hip_runtime.h>

#define Bb 32
#define Nn 4096
#define Dd 256
#define Hh 256
#define NCH 32
#define CHUNK 128
#define NSTEP 8            // K = 512 in steps of BK=64 (Q rows: steps 0-3, K rows: 4-7)

typedef __attribute__((ext_vector_type(8))) _Float16 half8;
typedef __attribute__((ext_vector_type(4))) float f32x4;

__device__ __forceinline__ float fast_tanhf(float x) {
    float e = __expf(2.0f * x);
    return 1.0f - 2.0f / (e + 1.0f);
}

__device__ __forceinline__ half8 cvt8(f32x4 v0, f32x4 v1) {
    half8 h;
    h[0] = (_Float16)v0.x; h[1] = (_Float16)v0.y;
    h[2] = (_Float16)v0.z; h[3] = (_Float16)v0.w;
    h[4] = (_Float16)v1.x; h[5] = (_Float16)v1.y;
    h[6] = (_Float16)v1.z; h[7] = (_Float16)v1.w;
    return h;
}

// ---------------------------------------------------------------------------
// Prep: Wcat = [Wq ; Wk] (H=256 rows, K=512 cols) -> f16 blob, fragment-linear:
// Wf[gs][j][l][e] = (f16) Wcat[j*16+(l&15)][gs*32+(l>>4)*8+e],  gs in [0,16)
// ---------------------------------------------------------------------------
__global__ __launch_bounds__(256) void prep_w_kernel(
    const float* __restrict__ Wq, const float* __restrict__ Wk,
    _Float16* __restrict__ Wf)
{
    const int g = blockIdx.x * 256 + threadIdx.x;      // [0, 16384)
    const int s = g >> 10;
    const int j = (g >> 6) & 15;
    const int l = g & 63;
    const int n = j * 16 + (l & 15);
    const int k = s * 32 + (l >> 4) * 8;
    const float* src = (k < 256) ? (Wq + n * 256 + k) : (Wk + n * 256 + (k - 256));
    const f32x4 v0 = *(const f32x4*)src;
    const f32x4 v1 = *(const f32x4*)(src + 4);
    *(half8*)&Wf[(size_t)g * 8] = cvt8(v0, v1);
}

// ---------------------------------------------------------------------------
// Scores, PRODUCER/CONSUMER. Block = 384 thr = 6 waves; tile 64 rows x 256 h.
// Waves 0-3 (consumers): cols [64w,64w+64), m=4 x n=4 x kk=2 -> 32 MFMA/step,
//   A-frags via lane-contiguous ds_read_b128 (conflict-free), B via L2 loads
//   issued one step early (drained by the NEXT barrier -> latency-free).
//   Consumers never wait on HBM.
// Waves 4-5 (producers): stream A (f32) with FULLY-COALESCED 32 B/lane reads
//   (8 whole lines per instr), depth-2 named-set pipeline (issue s+2 at step
//   s; cvt+write s+1 whose loads are ~2 steps old -> no stall), f32->f16 cvt
//   in-reg, ds_write_b128 into frag-linear LDS. Triple-buffered 8 KB tiles.
// One __syncthreads per step aligns roles.
// ---------------------------------------------------------------------------
__global__ __launch_bounds__(384, 3) void scores_pc_kernel(
    const float* __restrict__ Qm, const float* __restrict__ Km,
    const _Float16* __restrict__ Wf,
    const float* __restrict__ Wv, float* __restrict__ scores)
{
    __shared__ _Float16 Af[3][4096];    // 3 x 8 KB, frag-linear f16
    __shared__ float red[4][64];

    const int tid = threadIdx.x;
    const int lane = tid & 63;
    const int wave = tid >> 6;          // 0..5
    const size_t row0 = (size_t)blockIdx.x * 64;

    // ---------------- consumer state ----------------
    f32x4 acc[4][4];
#pragma unroll
    for (int m = 0; m < 4; ++m)
#pragma unroll
        for (int n = 0; n < 4; ++n) acc[m][n] = (f32x4){0.f, 0.f, 0.f, 0.f};
    float wv[4];
    half8 BA[8], BB[8];

    // ---------------- producer state ----------------
    // lane-chunk j=0..3: linear8 = j*128 + (wave-4)*64 + lane (32 B units)
    // r = linear8>>3 (row in tile), c8 = linear8&7 (k-chunk of 8 f32)
    f32x4 Pa[8], Pb[8];
    int roff[4], slot[4];

    if (wave < 4) {
#pragma unroll
        for (int n = 0; n < 4; ++n) wv[n] = Wv[wave * 64 + n * 16 + (lane & 15)];
    } else {
#pragma unroll
        for (int j = 0; j < 4; ++j) {
            const int lin = j * 128 + (wave - 4) * 64 + lane;
            const int r = lin >> 3;
            const int c8 = lin & 7;
            roff[j] = r * Dd + c8 * 8;
            const int kk = c8 >> 2, sub = c8 & 3, m = r >> 4, fl = (r & 15) + sub * 16;
            slot[j] = ((kk * 4 + m) * 64 + fl) * 8;
        }
    }

    auto loadB = [&](int s, half8* B) {
#pragma unroll
        for (int kk = 0; kk < 2; ++kk)
#pragma unroll
            for (int n = 0; n < 4; ++n)
                B[kk * 4 + n] = *(const half8*)(Wf +
                    ((size_t)((2 * s + kk) * 16 + wave * 4 + n) * 64 + lane) * 8);
    };
    auto issueP = [&](int s) {
        const float* base = (s < 4) ? (Qm + row0 * Dd + s * 64)
                                    : (Km + row0 * Dd + (s - 4) * 64);
#pragma unroll
        for (int j = 0; j < 4; ++j) {
            Pa[2 * j]     = *(const f32x4*)(base + roff[j]);
            Pa[2 * j + 1] = *(const f32x4*)(base + roff[j] + 4);
        }
    };
    auto issueQ = [&](int s) {
        const float* base = (s < 4) ? (Qm + row0 * Dd + s * 64)
                                    : (Km + row0 * Dd + (s - 4) * 64);
#pragma unroll
        for (int j = 0; j < 4; ++j) {
            Pb[2 * j]     = *(const f32x4*)(base + roff[j]);
            Pb[2 * j + 1] = *(const f32x4*)(base + roff[j] + 4);
        }
    };
    auto writeP = [&](int buf) {
#pragma unroll
        for (int j = 0; j < 4; ++j)
            *(half8*)&Af[buf][slot[j]] = cvt8(Pa[2 * j], Pa[2 * j + 1]);
    };
    auto writeQ = [&](int buf) {
#pragma unroll
        for (int j = 0; j < 4; ++j)
            *(half8*)&Af[buf][slot[j]] = cvt8(Pb[2 * j], Pb[2 * j + 1]);
    };
    auto mfma_step = [&](int buf, half8* B) {
#pragma unroll
        for (int kk = 0; kk < 2; ++kk)
#pragma unroll
            for (int m = 0; m < 4; ++m) {
                const half8 a = *(const half8*)&Af[buf][((kk * 4 + m) * 64 + lane) * 8];
#pragma unroll
                for (int n = 0; n < 4; ++n)
                    acc[m][n] = __builtin_amdgcn_mfma_f32_16x16x32_f16(a, B[kk * 4 + n], acc[m][n], 0, 0, 0);
            }
    };

    // prologue: producers fill buf0 (one-time stall) and preload step-1 set;
    // consumers preload B(0).
    if (wave < 4) {
        loadB(0, BA);
    } else {
        issueP(0);
        issueQ(1);
        writeP(0);
    }
    __syncthreads();

    // steps 0..7, fully unrolled (all %3 and guards compile-time)
#pragma unroll
    for (int s2 = 0; s2 < 4; ++s2) {
        const int s = 2 * s2;
        // even step s: consumers use BA, load BB(s+1); producers issueP(s+2), writeQ(s+1)
        if (wave < 4) {
            if (s + 1 < NSTEP) loadB(s + 1, BB);
            mfma_step(s % 3, BA);
        } else {
            if (s + 2 < NSTEP) issueP(s + 2);
            if (s + 1 < NSTEP) writeQ((s + 1) % 3);
        }
        __syncthreads();
        // odd step s+1: consumers use BB, load BA(s+2); producers issueQ(s+3), writeP(s+2)
        if (wave < 4) {
            if (s + 2 < NSTEP) loadB(s + 2, BA);
            mfma_step((s + 1) % 3, BB);
        } else {
            if (s + 3 < NSTEP) issueQ(s + 3);
            if (s + 2 < NSTEP) writeP((s + 2) % 3);
        }
        __syncthreads();
    }

    // Epilogue: score_row += Wv[col]*tanh(acc). C/D: col = lane&15,
    // row = m*16+(lane>>4)*4+r. Fixed-order reduce -> deterministic.
    if (wave < 4) {
        const int q = lane >> 4;
        float rp[4][4];
#pragma unroll
        for (int m = 0; m < 4; ++m)
#pragma unroll
            for (int r = 0; r < 4; ++r) {
                float v = 0.f;
#pragma unroll
                for (int n = 0; n < 4; ++n)
                    v += wv[n] * fast_tanhf(acc[m][n][r]);
                rp[m][r] = v;
            }
#pragma unroll
        for (int mask = 1; mask <= 8; mask <<= 1)
#pragma unroll
            for (int m = 0; m < 4; ++m)
#pragma unroll
                for (int r = 0; r < 4; ++r)
                    rp[m][r] += __shfl_xor(rp[m][r], mask, 64);
        if ((lane & 15) == 0) {
#pragma unroll
            for (int m = 0; m < 4; ++m)
#pragma unroll
                for (int r = 0; r < 4; ++r)
                    red[wave][m * 16 + q * 4 + r] = rp[m][r];
        }
    }
    __syncthreads();
    if (tid < 64)
        scores[row0 + tid] = (red[0][tid] + red[1][tid]) + (red[2][tid] + red[3][tid]);
}

// ---------------------------------------------------------------------------
// Per-b max + argmax + sum(exp). Argmax protected by f64 safety net:
// candidates within tau of max are recomputed exactly (f64 accumulation);
// pick by (exact score, lowest index). Deterministic: candidate SET is
// data-determined and the (value,index) argmax is order-independent.
// ---------------------------------------------------------------------------
#define MAXC 64
__global__ __launch_bounds__(256) void softmax_reduce_kernel(
    const float* __restrict__ scores,
    const float* __restrict__ Qg, const float* __restrict__ Kg,
    const float* __restrict__ Wq, const float* __restrict__ Wk,
    const float* __restrict__ Wv,
    float* __restrict__ mbuf, float* __restrict__ zbuf, float* __restrict__ out)
{
    __shared__ float sv[256];
    __shared__ int si[256];
    __shared__ double dred[256];
    __shared__ int cand[MAXC];
    __shared__ int cnt;
    const int b = blockIdx.x;
    const int tid = threadIdx.x;
    const float* sc = scores + (size_t)b * Nn;

    float best = -1e30f; int bi = 0;
    for (int j = 0; j < Nn / 256; ++j) {
        const int n = tid + j * 256;
        const float v = sc[n];
        if (v > best) { best = v; bi = n; }
    }
    sv[tid] = best; si[tid] = bi;
    __syncthreads();
    for (int off = 128; off > 0; off >>= 1) {
        if (tid < off) {
            const float v2 = sv[tid + off]; const int i2 = si[tid + off];
            if (v2 > sv[tid] || (v2 == sv[tid] && i2 < si[tid])) { sv[tid] = v2; si[tid] = i2; }
        }
        __syncthreads();
    }
    const float m = sv[0];
    int amax = si[0];
    __syncthreads();

    float ssum = 0.f;
    for (int j = 0; j < Nn / 256; ++j) ssum += __expf(sc[tid + j * 256] - m);
    sv[tid] = ssum;
    __syncthreads();
    for (int off = 128; off > 0; off >>= 1) {
        if (tid < off) sv[tid] += sv[tid + off];
        __syncthreads();
    }
    const float Z = sv[0];
    __syncthreads();

    if (tid == 0) cnt = 0;
    __syncthreads();
    const float tau = 0.02f;    // >> 5-sigma f16-GEMM score error (~1.4e-3 std)
    for (int j = 0; j < Nn / 256; ++j) {
        const int n = tid + j * 256;
        if (sc[n] >= m - tau) {
            const int p = atomicAdd(&cnt, 1);
            if (p < MAXC) cand[p] = n;
        }
    }
    __syncthreads();
    const int ncand = (cnt < MAXC) ? cnt : MAXC;
    if (ncand > 1) {
        double bestv = -1e300; int besti = 0x7fffffff;
        for (int c = 0; c < ncand; ++c) {
            const int n = cand[c];
            const float* qr = Qg + ((size_t)b * Nn + n) * Dd;
            const float* kr = Kg + ((size_t)b * Nn + n) * Dd;
            const float* wqr = Wq + tid * Dd;
            const float* wkr = Wk + tid * Dd;
            double accd = 0.0;
            for (int k2 = 0; k2 < Dd; ++k2)
                accd += (double)qr[k2] * (double)wqr[k2] + (double)kr[k2] * (double)wkr[k2];
            dred[tid] = (double)Wv[tid] * tanh(accd);
            __syncthreads();
            for (int off = 128; off > 0; off >>= 1) {
                if (tid < off) dred[tid] += dred[tid + off];
                __syncthreads();
            }
            const double s_c = dred[0];
            __syncthreads();
            if (s_c > bestv || (s_c == bestv && n < besti)) { bestv = s_c; besti = n; }
        }
        amax = besti;
    }

    if (tid == 0) {
        mbuf[b] = m;
        zbuf[b] = Z;
        out[(size_t)Bb * Dd + b] = (float)amax;
    }
}

// ---------------------------------------------------------------------------
// Partial out over n-chunks (no atomics; fixed-order accumulation)
// ---------------------------------------------------------------------------
__global__ __launch_bounds__(256) void partial_kernel(
    const float* __restrict__ V, const float* __restrict__ scores,
    const float* __restrict__ mbuf, float* __restrict__ part)
{
    __shared__ float e[CHUNK];
    const int c = blockIdx.x;
    const int b = blockIdx.y;
    const int tid = threadIdx.x;
    const float m = mbuf[b];
    if (tid < CHUNK)
        e[tid] = __expf(scores[(size_t)b * Nn + (size_t)c * CHUNK + tid] - m);
    __syncthreads();

    const float* vp = V + ((size_t)b * Nn + (size_t)c * CHUNK) * Dd + tid;
    float a0 = 0.f, a1 = 0.f, a2 = 0.f, a3 = 0.f;
    for (int n = 0; n < CHUNK; n += 4) {
        a0 = fmaf(e[n + 0], vp[(size_t)(n + 0) * Dd], a0);
        a1 = fmaf(e[n + 1], vp[(size_t)(n + 1) * Dd], a1);
        a2 = fmaf(e[n + 2], vp[(size_t)(n + 2) * Dd], a2);
        a3 = fmaf(e[n + 3], vp[(size_t)(n + 3) * Dd], a3);
    }
    part[((size_t)b * NCH + c) * Dd + tid] = ((a0 + a1) + (a2 + a3));
}

__global__ __launch_bounds__(256) void finalize_kernel(
    const float* __restrict__ part, const float* __restrict__ zbuf,
    float* __restrict__ out)
{
    const int b = blockIdx.x;
    const int tid = threadIdx.x;
    float s = 0.f;
#pragma unroll
    for (int c = 0; c < NCH; ++c) s += part[((size_t)b * NCH + c) * Dd + tid];
    out[(size_t)b * Dd + tid] = s / zbuf[b];
}

extern "C" void kernel_launch(void* const* d_in, const int* in_sizes, int n_in,
                              void* d_out, int out_size, void* d_ws, size_t ws_size,
                              hipStream_t stream) {
    const float* Q  = (const float*)d_in[0];
    const float* K  = (const float*)d_in[1];
    const float* V  = (const float*)d_in[2];
    const float* Wq = (const float*)d_in[3];
    const float* Wk = (const float*)d_in[4];
    const float* Wv = (const float*)d_in[5];
    float* out = (float*)d_out;

    // ws layout (bytes): Wf[256K] | scores[512K] | m[128] | z[128] | part[1M]
    char* wsb = (char*)d_ws;
    _Float16* Wf  = (_Float16*)(wsb);
    float* scores = (float*)(wsb + 262144);
    float* mbuf   = (float*)(wsb + 786432);
    float* zbuf   = (float*)(wsb + 786432 + 128);
    float* part   = (float*)(wsb + 786432 + 256);

    prep_w_kernel<<<dim3(64), dim3(256), 0, stream>>>(Wq, Wk, Wf);
    scores_pc_kernel<<<dim3((Bb * Nn) / 64), dim3(384), 0, stream>>>(Q, K, Wf, Wv, scores);
    softmax_reduce_kernel<<<dim3(Bb), dim3(256), 0, stream>>>(scores, Q, K, Wq, Wk, Wv, mbuf, zbuf, out);
    partial_kernel<<<dim3(NCH, Bb), dim3(256), 0, stream>>>(V, scores, mbuf, part);
    finalize_kernel<<<dim3(Bb), dim3(256), 0, stream>>>(part, zbuf, out);
}

// Round 13
// 158.015 us; speedup vs baseline: 2.1447x; 2.1447x over previous
//
#include <hip/hip_runtime.h>

#define Bb 32
#define Nn 4096
#define Dd 256
#define Hh 256
#define NCH 32
#define CHUNK 128

typedef __attribute__((ext_vector_type(8))) _Float16 half8;
typedef __attribute__((ext_vector_type(4))) float f32x4;

// direct global->LDS DMA, 16 B per lane; gp per-lane, lp wave-uniform
#define GLDS16(gp, lp) __builtin_amdgcn_global_load_lds( \
    (const __attribute__((address_space(1))) unsigned int*)(gp), \
    (__attribute__((address_space(3))) unsigned int*)(lp), 16, 0, 0)

__device__ __forceinline__ float fast_tanhf(float x) {
    float e = __expf(2.0f * x);
    return 1.0f - 2.0f / (e + 1.0f);
}

__device__ __forceinline__ half8 cvt8(f32x4 v0, f32x4 v1) {
    half8 h;
    h[0] = (_Float16)v0.x; h[1] = (_Float16)v0.y;
    h[2] = (_Float16)v0.z; h[3] = (_Float16)v0.w;
    h[4] = (_Float16)v1.x; h[5] = (_Float16)v1.y;
    h[6] = (_Float16)v1.z; h[7] = (_Float16)v1.w;
    return h;
}

// ---------------------------------------------------------------------------
// Prep: Wcat = [Wq ; Wk] (H=256 rows, K=512 cols) -> f16 blob, fragment-linear:
// Wf[gs][j][l][e] = (f16) Wcat[j*16+(l&15)][gs*32+(l>>4)*8+e],  gs in [0,16)
// ---------------------------------------------------------------------------
__global__ __launch_bounds__(256) void prep_w_kernel(
    const float* __restrict__ Wq, const float* __restrict__ Wk,
    _Float16* __restrict__ Wf)
{
    const int g = blockIdx.x * 256 + threadIdx.x;      // [0, 16384)
    const int s = g >> 10;
    const int j = (g >> 6) & 15;
    const int l = g & 63;
    const int n = j * 16 + (l & 15);
    const int k = s * 32 + (l >> 4) * 8;
    const float* src = (k < 256) ? (Wq + n * 256 + k) : (Wk + n * 256 + (k - 256));
    const f32x4 v0 = *(const f32x4*)src;
    const f32x4 v1 = *(const f32x4*)(src + 4);
    *(half8*)&Wf[(size_t)g * 8] = cvt8(v0, v1);
}

// ---------------------------------------------------------------------------
// Scores (R10 DMA skeleton, occupancy-tuned). Block = 64 rows x 256 h,
// 4 waves; wave w owns cols [64w,64w+64): m=4 x n=4 x kk=2, 16x16x32 f16.
// A staged by global_load_lds DMA into frag-linear f32 LDS (pre-permuted
// per-lane global source); B from L2-resident Wf each step.
// __launch_bounds__(256,4): target 4 blocks/CU so per-step latency of one
// block hides under the other three blocks' MFMA phases.
// ---------------------------------------------------------------------------
__global__ __launch_bounds__(256, 4) void scores_dma_kernel(
    const float* __restrict__ Q, const float* __restrict__ Kmat,
    const _Float16* __restrict__ Wf,
    const float* __restrict__ Wv, float* __restrict__ scores)
{
    __shared__ float Abuf[2][4096];    // 16 KB per buffer, frag-linear
    __shared__ float red[4][64];

    const int tid = threadIdx.x;
    const int lane = tid & 63;
    const int wave = tid >> 6;
    const size_t row0 = (size_t)blockIdx.x * 64;

    f32x4 acc[4][4];
#pragma unroll
    for (int m = 0; m < 4; ++m)
#pragma unroll
        for (int n = 0; n < 4; ++n) acc[m][n] = (f32x4){0.f, 0.f, 0.f, 0.f};

    float wv[4];
#pragma unroll
    for (int n = 0; n < 4; ++n) wv[n] = Wv[wave * 64 + n * 16 + (lane & 15)];

    // Per-thread DMA gather offsets (f32 elements), one per issue j=0..3.
    // Issue i = wave*4+j covers slots [i*32, i*32+32); lane l supplies the
    // 16 B for slot i*32+(l>>1), half (l&1):
    //   kk = i>>3, m = (i>>1)&3, row = m*16+((l>>1)&15),
    //   k = kk*32 + ((i&1)*2 + (l>>5))*8 + (l&1)*4
    int eoff[4];
#pragma unroll
    for (int j = 0; j < 4; ++j) {
        const int i = wave * 4 + j;
        const int kk = i >> 3;
        const int m  = (i >> 1) & 3;
        const int row_local = m * 16 + ((lane >> 1) & 15);
        const int kloc = kk * 32 + ((i & 1) * 2 + (lane >> 5)) * 8 + (lane & 1) * 4;
        eoff[j] = row_local * Dd + kloc;
    }

    half8 BB[8];
    auto issue_b = [&](int s) {
#pragma unroll
        for (int kk = 0; kk < 2; ++kk)
#pragma unroll
            for (int n = 0; n < 4; ++n)
                BB[kk * 4 + n] = *(const half8*)(Wf +
                    ((size_t)((s * 2 + kk) * 16 + wave * 4 + n) * 64 + lane) * 8);
    };
    auto dma_a = [&](int buf, int s) {
        const float* base = (s < 4) ? (Q    + row0 * Dd + s * 64)
                                    : (Kmat + row0 * Dd + (s - 4) * 64);
        char* lbase = (char*)&Abuf[buf][0] + wave * 4096;
#pragma unroll
        for (int j = 0; j < 4; ++j)
            GLDS16(base + eoff[j], lbase + j * 1024);
    };
    auto cluster = [&](int buf) {
#pragma unroll
        for (int kk = 0; kk < 2; ++kk)
#pragma unroll
            for (int m = 0; m < 4; ++m) {
                const float* fp = &Abuf[buf][(kk * 256 + m * 64 + lane) * 8];
                const f32x4 lo = *(const f32x4*)fp;
                const f32x4 hi = *(const f32x4*)(fp + 4);
                const half8 a = cvt8(lo, hi);
#pragma unroll
                for (int n = 0; n < 4; ++n)
                    acc[m][n] = __builtin_amdgcn_mfma_f32_16x16x32_f16(a, BB[kk * 4 + n], acc[m][n], 0, 0, 0);
            }
    };

    // prologue: DMA step 0 into buf0 (drained by the barrier)
    dma_a(0, 0);
    __syncthreads();

    for (int s = 0; s < 8; ++s) {
        issue_b(s);                       // L2 loads, consumed by this step's MFMA
        if (s < 7) dma_a((s + 1) & 1, s + 1);   // HBM DMA for next step
        cluster(s & 1);                   // waits B (counted vmcnt); DMA in flight
        __syncthreads();                  // drains DMA -> next buffer ready
    }

    // Epilogue: score_row += Wv[col]*tanh(acc). C/D: col = lane&15,
    // row = m*16+(lane>>4)*4+r. Fixed-order reduce -> deterministic.
    const int q = lane >> 4;
    float rp[4][4];
#pragma unroll
    for (int m = 0; m < 4; ++m)
#pragma unroll
        for (int r = 0; r < 4; ++r) {
            float v = 0.f;
#pragma unroll
            for (int n = 0; n < 4; ++n)
                v += wv[n] * fast_tanhf(acc[m][n][r]);
            rp[m][r] = v;
        }
#pragma unroll
    for (int mask = 1; mask <= 8; mask <<= 1)
#pragma unroll
        for (int m = 0; m < 4; ++m)
#pragma unroll
            for (int r = 0; r < 4; ++r)
                rp[m][r] += __shfl_xor(rp[m][r], mask, 64);

    if ((lane & 15) == 0) {
#pragma unroll
        for (int m = 0; m < 4; ++m)
#pragma unroll
            for (int r = 0; r < 4; ++r)
                red[wave][m * 16 + q * 4 + r] = rp[m][r];
    }
    __syncthreads();
    if (tid < 64)
        scores[row0 + tid] = (red[0][tid] + red[1][tid]) + (red[2][tid] + red[3][tid]);
}

// ---------------------------------------------------------------------------
// Argmax only (+f64 safety net). Softmax normalization moved to
// partial/finalize via RAW exp (scores bounded |s| < ~25 -> f32-safe).
// ---------------------------------------------------------------------------
#define MAXC 64
__global__ __launch_bounds__(256) void argmax_kernel(
    const float* __restrict__ scores,
    const float* __restrict__ Qg, const float* __restrict__ Kg,
    const float* __restrict__ Wq, const float* __restrict__ Wk,
    const float* __restrict__ Wv, float* __restrict__ out)
{
    __shared__ float sv[256];
    __shared__ int si[256];
    __shared__ double dred[256];
    __shared__ int cand[MAXC];
    __shared__ int cnt;
    const int b = blockIdx.x;
    const int tid = threadIdx.x;
    const float* sc = scores + (size_t)b * Nn;

    float best = -1e30f; int bi = 0;
    for (int j = 0; j < Nn / 256; ++j) {
        const int n = tid + j * 256;
        const float v = sc[n];
        if (v > best) { best = v; bi = n; }
    }
    sv[tid] = best; si[tid] = bi;
    __syncthreads();
    for (int off = 128; off > 0; off >>= 1) {
        if (tid < off) {
            const float v2 = sv[tid + off]; const int i2 = si[tid + off];
            if (v2 > sv[tid] || (v2 == sv[tid] && i2 < si[tid])) { sv[tid] = v2; si[tid] = i2; }
        }
        __syncthreads();
    }
    const float m = sv[0];
    int amax = si[0];
    __syncthreads();

    if (tid == 0) cnt = 0;
    __syncthreads();
    const float tau = 0.02f;    // >> 5-sigma f16-GEMM score error (~1.4e-3 std)
    for (int j = 0; j < Nn / 256; ++j) {
        const int n = tid + j * 256;
        if (sc[n] >= m - tau) {
            const int p = atomicAdd(&cnt, 1);
            if (p < MAXC) cand[p] = n;
        }
    }
    __syncthreads();
    const int ncand = (cnt < MAXC) ? cnt : MAXC;
    if (ncand > 1) {
        double bestv = -1e300; int besti = 0x7fffffff;
        for (int c = 0; c < ncand; ++c) {
            const int n = cand[c];
            const float* qr = Qg + ((size_t)b * Nn + n) * Dd;
            const float* kr = Kg + ((size_t)b * Nn + n) * Dd;
            const float* wqr = Wq + tid * Dd;
            const float* wkr = Wk + tid * Dd;
            double accd = 0.0;
            for (int k2 = 0; k2 < Dd; ++k2)
                accd += (double)qr[k2] * (double)wqr[k2] + (double)kr[k2] * (double)wkr[k2];
            dred[tid] = (double)Wv[tid] * tanh(accd);
            __syncthreads();
            for (int off = 128; off > 0; off >>= 1) {
                if (tid < off) dred[tid] += dred[tid + off];
                __syncthreads();
            }
            const double s_c = dred[0];
            __syncthreads();
            if (s_c > bestv || (s_c == bestv && n < besti)) { bestv = s_c; besti = n; }
        }
        amax = besti;
    }

    if (tid == 0)
        out[(size_t)Bb * Dd + b] = (float)amax;
}

// ---------------------------------------------------------------------------
// Partial out over n-chunks, RAW exp (no max subtraction needed; |s| < ~25).
// Also emits per-chunk exp-sum pz. No atomics; fixed-order -> deterministic.
// ---------------------------------------------------------------------------
__global__ __launch_bounds__(256) void partial_kernel(
    const float* __restrict__ V, const float* __restrict__ scores,
    float* __restrict__ part, float* __restrict__ pz)
{
    __shared__ float e[CHUNK];
    const int c = blockIdx.x;
    const int b = blockIdx.y;
    const int tid = threadIdx.x;
    if (tid < CHUNK)
        e[tid] = __expf(scores[(size_t)b * Nn + (size_t)c * CHUNK + tid]);
    __syncthreads();

    if (tid == 0) {       // serial fixed-order chunk exp-sum (cheap vs V loop)
        float s = 0.f;
        for (int n = 0; n < CHUNK; ++n) s += e[n];
        pz[b * NCH + c] = s;
    }

    const float* vp = V + ((size_t)b * Nn + (size_t)c * CHUNK) * Dd + tid;
    float a0 = 0.f, a1 = 0.f, a2 = 0.f, a3 = 0.f;
    for (int n = 0; n < CHUNK; n += 4) {
        a0 = fmaf(e[n + 0], vp[(size_t)(n + 0) * Dd], a0);
        a1 = fmaf(e[n + 1], vp[(size_t)(n + 1) * Dd], a1);
        a2 = fmaf(e[n + 2], vp[(size_t)(n + 2) * Dd], a2);
        a3 = fmaf(e[n + 3], vp[(size_t)(n + 3) * Dd], a3);
    }
    part[((size_t)b * NCH + c) * Dd + tid] = ((a0 + a1) + (a2 + a3));
}

__global__ __launch_bounds__(256) void finalize_kernel(
    const float* __restrict__ part, const float* __restrict__ pz,
    float* __restrict__ out)
{
    __shared__ float zsh;
    const int b = blockIdx.x;
    const int tid = threadIdx.x;
    if (tid == 0) {
        float z = 0.f;
        for (int c = 0; c < NCH; ++c) z += pz[b * NCH + c];
        zsh = z;
    }
    float s = 0.f;
#pragma unroll
    for (int c = 0; c < NCH; ++c) s += part[((size_t)b * NCH + c) * Dd + tid];
    __syncthreads();
    out[(size_t)b * Dd + tid] = s / zsh;
}

extern "C" void kernel_launch(void* const* d_in, const int* in_sizes, int n_in,
                              void* d_out, int out_size, void* d_ws, size_t ws_size,
                              hipStream_t stream) {
    const float* Q  = (const float*)d_in[0];
    const float* K  = (const float*)d_in[1];
    const float* V  = (const float*)d_in[2];
    const float* Wq = (const float*)d_in[3];
    const float* Wk = (const float*)d_in[4];
    const float* Wv = (const float*)d_in[5];
    float* out = (float*)d_out;

    // ws layout (bytes): Wf[256K] | scores[512K] | part[1M] | pz[4K]
    char* wsb = (char*)d_ws;
    _Float16* Wf  = (_Float16*)(wsb);
    float* scores = (float*)(wsb + 262144);
    float* part   = (float*)(wsb + 786432);
    float* pz     = (float*)(wsb + 786432 + 1048576);

    prep_w_kernel<<<dim3(64), dim3(256), 0, stream>>>(Wq, Wk, Wf);
    scores_dma_kernel<<<dim3((Bb * Nn) / 64), dim3(256), 0, stream>>>(Q, K, Wf, Wv, scores);
    partial_kernel<<<dim3(NCH, Bb), dim3(256), 0, stream>>>(V, scores, part, pz);
    argmax_kernel<<<dim3(Bb), dim3(256), 0, stream>>>(scores, Q, K, Wq, Wk, Wv, out);
    finalize_kernel<<<dim3(Bb), dim3(256), 0, stream>>>(part, pz, out);
}

// Round 14
// 147.825 us; speedup vs baseline: 2.2926x; 1.0689x over previous
//
#include <hip/hip_runtime.h>

#define Bb 32
#define Nn 4096
#define Dd 256
#define Hh 256

typedef __attribute__((ext_vector_type(8))) _Float16 half8;
typedef __attribute__((ext_vector_type(4))) float f32x4;

// direct global->LDS DMA, 16 B per lane; gp per-lane, lp wave-uniform
#define GLDS16(gp, lp) __builtin_amdgcn_global_load_lds( \
    (const __attribute__((address_space(1))) unsigned int*)(gp), \
    (__attribute__((address_space(3))) unsigned int*)(lp), 16, 0, 0)

__device__ __forceinline__ float fast_tanhf(float x) {
    float e = __expf(2.0f * x);
    return 1.0f - 2.0f / (e + 1.0f);
}

__device__ __forceinline__ half8 cvt8(f32x4 v0, f32x4 v1) {
    half8 h;
    h[0] = (_Float16)v0.x; h[1] = (_Float16)v0.y;
    h[2] = (_Float16)v0.z; h[3] = (_Float16)v0.w;
    h[4] = (_Float16)v1.x; h[5] = (_Float16)v1.y;
    h[6] = (_Float16)v1.z; h[7] = (_Float16)v1.w;
    return h;
}

// ---------------------------------------------------------------------------
// Prep: Wcat = [Wq ; Wk] (H=256 rows, K=512 cols) -> f16 blob, fragment-linear:
// Wf[gs][j][l][e] = (f16) Wcat[j*16+(l&15)][gs*32+(l>>4)*8+e],  gs in [0,16)
// ---------------------------------------------------------------------------
__global__ __launch_bounds__(256) void prep_w_kernel(
    const float* __restrict__ Wq, const float* __restrict__ Wk,
    _Float16* __restrict__ Wf)
{
    const int g = blockIdx.x * 256 + threadIdx.x;      // [0, 16384)
    const int s = g >> 10;
    const int j = (g >> 6) & 15;
    const int l = g & 63;
    const int n = j * 16 + (l & 15);
    const int k = s * 32 + (l >> 4) * 8;
    const float* src = (k < 256) ? (Wq + n * 256 + k) : (Wk + n * 256 + (k - 256));
    const f32x4 v0 = *(const f32x4*)src;
    const f32x4 v1 = *(const f32x4*)(src + 4);
    *(half8*)&Wf[(size_t)g * 8] = cvt8(v0, v1);
}

// ---------------------------------------------------------------------------
// Fused scores + V-aggregation. Block = 64 rows x 256 h, 4 waves (R10 DMA
// skeleton, launch_bounds(256,3)). After the score epilogue, the block
// computes e_r = exp(score_r) (RAW exp; |s|<~25 so f32-safe, validated R13)
// and streams its own V tile (64 rows x 256 cols, coalesced): thread d owns
// col d, part[bid][d] = sum_r e_r * V[row0+r][d]; pz[bid] = sum_r e_r.
// The V phase is pure BW work that staggers across blocks and fills the
// latency bubbles of other blocks' MFMA phases.
// ---------------------------------------------------------------------------
__global__ __launch_bounds__(256, 3) void scores_fused_kernel(
    const float* __restrict__ Q, const float* __restrict__ Kmat,
    const float* __restrict__ V, const _Float16* __restrict__ Wf,
    const float* __restrict__ Wv, float* __restrict__ scores,
    float* __restrict__ part, float* __restrict__ pz)
{
    __shared__ float Abuf[2][4096];    // 16 KB per buffer, frag-linear
    __shared__ float red[4][64];
    __shared__ float ex[64];

    const int tid = threadIdx.x;
    const int lane = tid & 63;
    const int wave = tid >> 6;
    const size_t row0 = (size_t)blockIdx.x * 64;

    f32x4 acc[4][4];
#pragma unroll
    for (int m = 0; m < 4; ++m)
#pragma unroll
        for (int n = 0; n < 4; ++n) acc[m][n] = (f32x4){0.f, 0.f, 0.f, 0.f};

    float wv[4];
#pragma unroll
    for (int n = 0; n < 4; ++n) wv[n] = Wv[wave * 64 + n * 16 + (lane & 15)];

    // Per-thread DMA gather offsets (f32 elements), one per issue j=0..3.
    // Issue i = wave*4+j covers slots [i*32, i*32+32); lane l supplies the
    // 16 B for slot i*32+(l>>1), half (l&1):
    //   kk = i>>3, m = (i>>1)&3, row = m*16+((l>>1)&15),
    //   k = kk*32 + ((i&1)*2 + (l>>5))*8 + (l&1)*4
    int eoff[4];
#pragma unroll
    for (int j = 0; j < 4; ++j) {
        const int i = wave * 4 + j;
        const int kk = i >> 3;
        const int m  = (i >> 1) & 3;
        const int row_local = m * 16 + ((lane >> 1) & 15);
        const int kloc = kk * 32 + ((i & 1) * 2 + (lane >> 5)) * 8 + (lane & 1) * 4;
        eoff[j] = row_local * Dd + kloc;
    }

    half8 BB[8];
    auto issue_b = [&](int s) {
#pragma unroll
        for (int kk = 0; kk < 2; ++kk)
#pragma unroll
            for (int n = 0; n < 4; ++n)
                BB[kk * 4 + n] = *(const half8*)(Wf +
                    ((size_t)((s * 2 + kk) * 16 + wave * 4 + n) * 64 + lane) * 8);
    };
    auto dma_a = [&](int buf, int s) {
        const float* base = (s < 4) ? (Q    + row0 * Dd + s * 64)
                                    : (Kmat + row0 * Dd + (s - 4) * 64);
        char* lbase = (char*)&Abuf[buf][0] + wave * 4096;
#pragma unroll
        for (int j = 0; j < 4; ++j)
            GLDS16(base + eoff[j], lbase + j * 1024);
    };
    auto cluster = [&](int buf) {
#pragma unroll
        for (int kk = 0; kk < 2; ++kk)
#pragma unroll
            for (int m = 0; m < 4; ++m) {
                const float* fp = &Abuf[buf][(kk * 256 + m * 64 + lane) * 8];
                const f32x4 lo = *(const f32x4*)fp;
                const f32x4 hi = *(const f32x4*)(fp + 4);
                const half8 a = cvt8(lo, hi);
#pragma unroll
                for (int n = 0; n < 4; ++n)
                    acc[m][n] = __builtin_amdgcn_mfma_f32_16x16x32_f16(a, BB[kk * 4 + n], acc[m][n], 0, 0, 0);
            }
    };

    // prologue: DMA step 0 into buf0 (drained by the barrier)
    dma_a(0, 0);
    __syncthreads();

    for (int s = 0; s < 8; ++s) {
        issue_b(s);                       // L2 loads, consumed by this step's MFMA
        if (s < 7) dma_a((s + 1) & 1, s + 1);   // HBM DMA for next step
        cluster(s & 1);                   // waits B (counted vmcnt); DMA in flight
        __syncthreads();                  // drains DMA -> next buffer ready
    }

    // Score epilogue: score_row += Wv[col]*tanh(acc). C/D: col = lane&15,
    // row = m*16+(lane>>4)*4+r. Fixed-order reduce -> deterministic.
    const int q = lane >> 4;
    float rp[4][4];
#pragma unroll
    for (int m = 0; m < 4; ++m)
#pragma unroll
        for (int r = 0; r < 4; ++r) {
            float v = 0.f;
#pragma unroll
            for (int n = 0; n < 4; ++n)
                v += wv[n] * fast_tanhf(acc[m][n][r]);
            rp[m][r] = v;
        }
#pragma unroll
    for (int mask = 1; mask <= 8; mask <<= 1)
#pragma unroll
        for (int m = 0; m < 4; ++m)
#pragma unroll
            for (int r = 0; r < 4; ++r)
                rp[m][r] += __shfl_xor(rp[m][r], mask, 64);

    if ((lane & 15) == 0) {
#pragma unroll
        for (int m = 0; m < 4; ++m)
#pragma unroll
            for (int r = 0; r < 4; ++r)
                red[wave][m * 16 + q * 4 + r] = rp[m][r];
    }
    __syncthreads();
    if (tid < 64) {
        const float s = (red[0][tid] + red[1][tid]) + (red[2][tid] + red[3][tid]);
        scores[row0 + tid] = s;
        ex[tid] = __expf(s);              // raw exp: safe, |s| bounded
    }
    __syncthreads();

    // V phase: thread d = tid aggregates its column over the 64 rows.
    // Coalesced: consecutive threads -> consecutive addresses.
    {
        const float* vp = V + row0 * Dd + tid;
        float a0 = 0.f, a1 = 0.f, a2 = 0.f, a3 = 0.f;
        for (int r = 0; r < 64; r += 4) {
            a0 = fmaf(ex[r + 0], vp[(size_t)(r + 0) * Dd], a0);
            a1 = fmaf(ex[r + 1], vp[(size_t)(r + 1) * Dd], a1);
            a2 = fmaf(ex[r + 2], vp[(size_t)(r + 2) * Dd], a2);
            a3 = fmaf(ex[r + 3], vp[(size_t)(r + 3) * Dd], a3);
        }
        part[(size_t)blockIdx.x * Dd + tid] = ((a0 + a1) + (a2 + a3));
        if (tid == 0) {
            float z = 0.f;
            for (int r = 0; r < 64; ++r) z += ex[r];   // fixed order
            pz[blockIdx.x] = z;
        }
    }
}

// ---------------------------------------------------------------------------
// Argmax only (+f64 safety net). Deterministic: candidate SET is data-
// determined and the (value,index) argmax is order-independent.
// ---------------------------------------------------------------------------
#define MAXC 64
__global__ __launch_bounds__(256) void argmax_kernel(
    const float* __restrict__ scores,
    const float* __restrict__ Qg, const float* __restrict__ Kg,
    const float* __restrict__ Wq, const float* __restrict__ Wk,
    const float* __restrict__ Wv, float* __restrict__ out)
{
    __shared__ float sv[256];
    __shared__ int si[256];
    __shared__ double dred[256];
    __shared__ int cand[MAXC];
    __shared__ int cnt;
    const int b = blockIdx.x;
    const int tid = threadIdx.x;
    const float* sc = scores + (size_t)b * Nn;

    float best = -1e30f; int bi = 0;
    for (int j = 0; j < Nn / 256; ++j) {
        const int n = tid + j * 256;
        const float v = sc[n];
        if (v > best) { best = v; bi = n; }
    }
    sv[tid] = best; si[tid] = bi;
    __syncthreads();
    for (int off = 128; off > 0; off >>= 1) {
        if (tid < off) {
            const float v2 = sv[tid + off]; const int i2 = si[tid + off];
            if (v2 > sv[tid] || (v2 == sv[tid] && i2 < si[tid])) { sv[tid] = v2; si[tid] = i2; }
        }
        __syncthreads();
    }
    const float m = sv[0];
    int amax = si[0];
    __syncthreads();

    if (tid == 0) cnt = 0;
    __syncthreads();
    const float tau = 0.02f;    // >> 5-sigma f16-GEMM score error (~1.4e-3 std)
    for (int j = 0; j < Nn / 256; ++j) {
        const int n = tid + j * 256;
        if (sc[n] >= m - tau) {
            const int p = atomicAdd(&cnt, 1);
            if (p < MAXC) cand[p] = n;
        }
    }
    __syncthreads();
    const int ncand = (cnt < MAXC) ? cnt : MAXC;
    if (ncand > 1) {
        double bestv = -1e300; int besti = 0x7fffffff;
        for (int c = 0; c < ncand; ++c) {
            const int n = cand[c];
            const float* qr = Qg + ((size_t)b * Nn + n) * Dd;
            const float* kr = Kg + ((size_t)b * Nn + n) * Dd;
            const float* wqr = Wq + tid * Dd;
            const float* wkr = Wk + tid * Dd;
            double accd = 0.0;
            for (int k2 = 0; k2 < Dd; ++k2)
                accd += (double)qr[k2] * (double)wqr[k2] + (double)kr[k2] * (double)wkr[k2];
            dred[tid] = (double)Wv[tid] * tanh(accd);
            __syncthreads();
            for (int off = 128; off > 0; off >>= 1) {
                if (tid < off) dred[tid] += dred[tid + off];
                __syncthreads();
            }
            const double s_c = dred[0];
            __syncthreads();
            if (s_c > bestv || (s_c == bestv && n < besti)) { bestv = s_c; besti = n; }
        }
        amax = besti;
    }

    if (tid == 0)
        out[(size_t)Bb * Dd + b] = (float)amax;
}

// ---------------------------------------------------------------------------
// Finalize: out[b][d] = (sum of 64 chunk partials) / (sum of 64 chunk pz).
// Fixed order -> deterministic.
// ---------------------------------------------------------------------------
__global__ __launch_bounds__(256) void finalize_kernel(
    const float* __restrict__ part, const float* __restrict__ pz,
    float* __restrict__ out)
{
    __shared__ float zsh;
    const int b = blockIdx.x;
    const int tid = threadIdx.x;
    if (tid == 0) {
        float z = 0.f;
        for (int c = 0; c < 64; ++c) z += pz[b * 64 + c];
        zsh = z;
    }
    float s = 0.f;
#pragma unroll
    for (int c = 0; c < 64; ++c) s += part[((size_t)b * 64 + c) * Dd + tid];
    __syncthreads();
    out[(size_t)b * Dd + tid] = s / zsh;
}

extern "C" void kernel_launch(void* const* d_in, const int* in_sizes, int n_in,
                              void* d_out, int out_size, void* d_ws, size_t ws_size,
                              hipStream_t stream) {
    const float* Q  = (const float*)d_in[0];
    const float* K  = (const float*)d_in[1];
    const float* V  = (const float*)d_in[2];
    const float* Wq = (const float*)d_in[3];
    const float* Wk = (const float*)d_in[4];
    const float* Wv = (const float*)d_in[5];
    float* out = (float*)d_out;

    // ws layout (bytes): Wf[256K] | scores[512K] | part[2M] | pz[8K]
    char* wsb = (char*)d_ws;
    _Float16* Wf  = (_Float16*)(wsb);
    float* scores = (float*)(wsb + 262144);
    float* part   = (float*)(wsb + 786432);
    float* pz     = (float*)(wsb + 786432 + 2097152);

    prep_w_kernel<<<dim3(64), dim3(256), 0, stream>>>(Wq, Wk, Wf);
    scores_fused_kernel<<<dim3((Bb * Nn) / 64), dim3(256), 0, stream>>>(
        Q, K, V, Wf, Wv, scores, part, pz);
    argmax_kernel<<<dim3(Bb), dim3(256), 0, stream>>>(scores, Q, K, Wq, Wk, Wv, out);
    finalize_kernel<<<dim3(Bb), dim3(256), 0, stream>>>(part, pz, out);
}

// Round 15
// 141.095 us; speedup vs baseline: 2.4019x; 1.0477x over previous
//
#include <hip/hip_runtime.h>

#define Bb 32
#define Nn 4096
#define Dd 256
#define Hh 256
#define NCH 32
#define CHUNK 128
#define NSTEPS 16   // K = 512 (Q:256 then K:256), steps of 32

typedef __attribute__((ext_vector_type(8))) _Float16 half8;
typedef __attribute__((ext_vector_type(4))) float f32x4;

__device__ __forceinline__ float fast_tanhf(float x) {
    float e = __expf(2.0f * x);
    return 1.0f - 2.0f / (e + 1.0f);
}

__device__ __forceinline__ half8 cvt8(f32x4 v0, f32x4 v1) {
    half8 h;
    h[0] = (_Float16)v0.x; h[1] = (_Float16)v0.y;
    h[2] = (_Float16)v0.z; h[3] = (_Float16)v0.w;
    h[4] = (_Float16)v1.x; h[5] = (_Float16)v1.y;
    h[6] = (_Float16)v1.z; h[7] = (_Float16)v1.w;
    return h;
}

// ---------------------------------------------------------------------------
// Prep: Wcat = [Wq ; Wk] (H=256 rows, K=512 cols) -> f16 blob, fragment-linear:
// Wf[s][j][l][e] = (f16) Wcat[j*16+(l&15)][s*32+(l>>4)*8+e]
// ---------------------------------------------------------------------------
__global__ __launch_bounds__(256) void prep_w_kernel(
    const float* __restrict__ Wq, const float* __restrict__ Wk,
    _Float16* __restrict__ Wf)
{
    const int g = blockIdx.x * 256 + threadIdx.x;      // [0, 16384)
    const int s = g >> 10;
    const int j = (g >> 6) & 15;
    const int l = g & 63;
    const int n = j * 16 + (l & 15);
    const int k = s * 32 + (l >> 4) * 8;
    const float* src = (k < 256) ? (Wq + n * 256 + k) : (Wk + n * 256 + (k - 256));
    const f32x4 v0 = *(const f32x4*)src;
    const f32x4 v1 = *(const f32x4*)(src + 4);
    *(half8*)&Wf[(size_t)g * 8] = cvt8(v0, v1);
}

// ---------------------------------------------------------------------------
// Scores: R6 champion schedule, re-dimensioned for occupancy.
// Block = 512 thr = 8 waves, tile 128 rows x 256 h. Wave w owns cols
// [32w, 32w+32): m=8 x n=2 tiles of 16x16x32 f16 -> acc = 64 AGPR/wave
// (half of R6's 128), targeting 4 waves/SIMD = 2 co-resident blocks/CU.
// A pipeline depth 2 (P/Q reg sets), LDS triple-buffered f16 frag-linear;
// B reg-double-buffered (BA/BB) from L2-resident prep blob.
// ---------------------------------------------------------------------------
__global__ __launch_bounds__(512, 4) void scores_mfma_kernel(
    const float* __restrict__ Q, const float* __restrict__ Kmat,
    const _Float16* __restrict__ Wf,
    const float* __restrict__ Wv, float* __restrict__ scores)
{
    __shared__ _Float16 Ahf[3][4096];   // [buf][(m*64+lane)*8+e]  (8 KB each)
    __shared__ float red[8][128];

    const int tid = threadIdx.x;        // 0..511
    const int lane = tid & 63;
    const int wave = tid >> 6;          // 0..7
    const size_t row0 = (size_t)blockIdx.x * 128;

    f32x4 acc[8][2];
#pragma unroll
    for (int m = 0; m < 8; ++m)
#pragma unroll
        for (int n = 0; n < 2; ++n) acc[m][n] = (f32x4){0.f, 0.f, 0.f, 0.f};

    float wv[2];
#pragma unroll
    for (int n = 0; n < 2; ++n) wv[n] = Wv[wave * 32 + n * 16 + (lane & 15)];

    // staging: thread t owns frag slot t. slot: m = t>>6 (= wave), l = t&63,
    // row = m*16+(l&15), k-chunk = (l>>4)*8. 8 f32 per thread, coalesced.
    const int srow = wave * 16 + (lane & 15);
    const int skf  = (lane >> 4) * 8;

    f32x4 pA0, pA1;                    // P: even-step data
    f32x4 qA0, qA1;                    // Q: odd-step data
    half8 BA[2], BB[2];

    auto issue_aP = [&](int s) {
        const float* Asrc = (s < 8) ? Q : Kmat;
        const float* p = Asrc + (row0 + srow) * Dd + (s & 7) * 32 + skf;
        pA0 = *(const f32x4*)p; pA1 = *(const f32x4*)(p + 4);
    };
    auto issue_aQ = [&](int s) {
        const float* Asrc = (s < 8) ? Q : Kmat;
        const float* p = Asrc + (row0 + srow) * Dd + (s & 7) * 32 + skf;
        qA0 = *(const f32x4*)p; qA1 = *(const f32x4*)(p + 4);
    };
    auto issue_bA = [&](int s) {
#pragma unroll
        for (int n = 0; n < 2; ++n)
            BA[n] = *(const half8*)(Wf + ((size_t)(s * 16 + wave * 2 + n) * 64 + lane) * 8);
    };
    auto issue_bB = [&](int s) {
#pragma unroll
        for (int n = 0; n < 2; ++n)
            BB[n] = *(const half8*)(Wf + ((size_t)(s * 16 + wave * 2 + n) * 64 + lane) * 8);
    };
    auto storeP = [&](int buf) {
        *(half8*)&Ahf[buf][tid * 8] = cvt8(pA0, pA1);
    };
    auto storeQ = [&](int buf) {
        *(half8*)&Ahf[buf][tid * 8] = cvt8(qA0, qA1);
    };
    auto clusterA = [&](int rb) {
        __builtin_amdgcn_s_setprio(1);
#pragma unroll
        for (int m = 0; m < 8; ++m) {
            const half8 a = *(const half8*)&Ahf[rb][(m * 64 + lane) * 8];
            acc[m][0] = __builtin_amdgcn_mfma_f32_16x16x32_f16(a, BA[0], acc[m][0], 0, 0, 0);
            acc[m][1] = __builtin_amdgcn_mfma_f32_16x16x32_f16(a, BA[1], acc[m][1], 0, 0, 0);
        }
        __builtin_amdgcn_s_setprio(0);
    };
    auto clusterB = [&](int rb) {
        __builtin_amdgcn_s_setprio(1);
#pragma unroll
        for (int m = 0; m < 8; ++m) {
            const half8 a = *(const half8*)&Ahf[rb][(m * 64 + lane) * 8];
            acc[m][0] = __builtin_amdgcn_mfma_f32_16x16x32_f16(a, BB[0], acc[m][0], 0, 0, 0);
            acc[m][1] = __builtin_amdgcn_mfma_f32_16x16x32_f16(a, BB[1], acc[m][1], 0, 0, 0);
        }
        __builtin_amdgcn_s_setprio(0);
    };

    // prologue: P<-A0, Q<-A1, BA<-B0; store A0 into LDS0
    issue_aP(0);
    issue_aQ(1);
    issue_bA(0);
    storeP(0);
    __syncthreads();

    // steady state (steps 0..13), rb(s) = s%3
    int rb = 0;
    for (int s2 = 0; s2 < 7; ++s2) {
        const int s = 2 * s2;
        const int rb1 = (rb == 2) ? 0 : rb + 1;
        const int rb2 = (rb1 == 2) ? 0 : rb1 + 1;
        // even step s: consume LDS[rb] with BA=B(s)
        issue_bB(s + 1);
        issue_aP(s + 2);
        clusterA(rb);
        storeQ(rb1);          // A(s+1), loaded at s-1
        __syncthreads();
        // odd step s+1: consume LDS[rb1] with BB=B(s+1)
        issue_bA(s + 2);
        issue_aQ(s + 3);
        clusterB(rb1);
        storeP(rb2);          // A(s+2), loaded at s
        __syncthreads();
        rb = rb2;
    }
    // step 14 (rb==2): BA=B14 (loaded at step 13)
    issue_bB(15);
    clusterA(2);
    storeQ(0);                // A15 (loaded at step 13)
    __syncthreads();
    // step 15
    clusterB(0);

    // Epilogue: score_row += Wv[col]*tanh(acc). C/D: col = wave*32+n*16+(lane&15),
    // row = m*16+(lane>>4)*4+r. Fixed-order reduce -> deterministic.
    const int q = lane >> 4;
    float rp[8][4];
#pragma unroll
    for (int m = 0; m < 8; ++m)
#pragma unroll
        for (int r = 0; r < 4; ++r)
            rp[m][r] = wv[0] * fast_tanhf(acc[m][0][r]) + wv[1] * fast_tanhf(acc[m][1][r]);
#pragma unroll
    for (int mask = 1; mask <= 8; mask <<= 1)
#pragma unroll
        for (int m = 0; m < 8; ++m)
#pragma unroll
            for (int r = 0; r < 4; ++r)
                rp[m][r] += __shfl_xor(rp[m][r], mask, 64);

    if ((lane & 15) == 0) {
#pragma unroll
        for (int m = 0; m < 8; ++m)
#pragma unroll
            for (int r = 0; r < 4; ++r)
                red[wave][m * 16 + q * 4 + r] = rp[m][r];
    }
    __syncthreads();
    if (tid < 128) {
        float s = 0.f;
#pragma unroll
        for (int w = 0; w < 8; ++w) s += red[w][tid];
        scores[row0 + tid] = s;
    }
}

// ---------------------------------------------------------------------------
// Per-b max + argmax + sum(exp). Argmax protected by f64 safety net:
// candidates within tau of max are recomputed exactly (f64 accumulation);
// pick by (exact score, lowest index). Deterministic.
// ---------------------------------------------------------------------------
#define MAXC 64
__global__ __launch_bounds__(256) void softmax_reduce_kernel(
    const float* __restrict__ scores,
    const float* __restrict__ Qg, const float* __restrict__ Kg,
    const float* __restrict__ Wq, const float* __restrict__ Wk,
    const float* __restrict__ Wv,
    float* __restrict__ mbuf, float* __restrict__ zbuf, float* __restrict__ out)
{
    __shared__ float sv[256];
    __shared__ int si[256];
    __shared__ double dred[256];
    __shared__ int cand[MAXC];
    __shared__ int cnt;
    const int b = blockIdx.x;
    const int tid = threadIdx.x;
    const float* sc = scores + (size_t)b * Nn;

    float best = -1e30f; int bi = 0;
    for (int j = 0; j < Nn / 256; ++j) {
        const int n = tid + j * 256;
        const float v = sc[n];
        if (v > best) { best = v; bi = n; }
    }
    sv[tid] = best; si[tid] = bi;
    __syncthreads();
    for (int off = 128; off > 0; off >>= 1) {
        if (tid < off) {
            const float v2 = sv[tid + off]; const int i2 = si[tid + off];
            if (v2 > sv[tid] || (v2 == sv[tid] && i2 < si[tid])) { sv[tid] = v2; si[tid] = i2; }
        }
        __syncthreads();
    }
    const float m = sv[0];
    int amax = si[0];
    __syncthreads();

    float ssum = 0.f;
    for (int j = 0; j < Nn / 256; ++j) ssum += __expf(sc[tid + j * 256] - m);
    sv[tid] = ssum;
    __syncthreads();
    for (int off = 128; off > 0; off >>= 1) {
        if (tid < off) sv[tid] += sv[tid + off];
        __syncthreads();
    }
    const float Z = sv[0];
    __syncthreads();

    if (tid == 0) cnt = 0;
    __syncthreads();
    const float tau = 0.02f;    // >> 5-sigma f16-GEMM score error (~1.4e-3 std)
    for (int j = 0; j < Nn / 256; ++j) {
        const int n = tid + j * 256;
        if (sc[n] >= m - tau) {
            const int p = atomicAdd(&cnt, 1);
            if (p < MAXC) cand[p] = n;
        }
    }
    __syncthreads();
    const int ncand = (cnt < MAXC) ? cnt : MAXC;
    if (ncand > 1) {
        double bestv = -1e300; int besti = 0x7fffffff;
        for (int c = 0; c < ncand; ++c) {
            const int n = cand[c];
            const float* qr = Qg + ((size_t)b * Nn + n) * Dd;
            const float* kr = Kg + ((size_t)b * Nn + n) * Dd;
            const float* wqr = Wq + tid * Dd;
            const float* wkr = Wk + tid * Dd;
            double accd = 0.0;
            for (int k2 = 0; k2 < Dd; ++k2)
                accd += (double)qr[k2] * (double)wqr[k2] + (double)kr[k2] * (double)wkr[k2];
            dred[tid] = (double)Wv[tid] * tanh(accd);
            __syncthreads();
            for (int off = 128; off > 0; off >>= 1) {
                if (tid < off) dred[tid] += dred[tid + off];
                __syncthreads();
            }
            const double s_c = dred[0];
            __syncthreads();
            if (s_c > bestv || (s_c == bestv && n < besti)) { bestv = s_c; besti = n; }
        }
        amax = besti;
    }

    if (tid == 0) {
        mbuf[b] = m;
        zbuf[b] = Z;
        out[(size_t)Bb * Dd + b] = (float)amax;
    }
}

// ---------------------------------------------------------------------------
// Partial out over n-chunks (no atomics; fixed-order accumulation)
// ---------------------------------------------------------------------------
__global__ __launch_bounds__(256) void partial_kernel(
    const float* __restrict__ V, const float* __restrict__ scores,
    const float* __restrict__ mbuf, float* __restrict__ part)
{
    __shared__ float e[CHUNK];
    const int c = blockIdx.x;
    const int b = blockIdx.y;
    const int tid = threadIdx.x;
    const float m = mbuf[b];
    if (tid < CHUNK)
        e[tid] = __expf(scores[(size_t)b * Nn + (size_t)c * CHUNK + tid] - m);
    __syncthreads();

    const float* vp = V + ((size_t)b * Nn + (size_t)c * CHUNK) * Dd + tid;
    float a0 = 0.f, a1 = 0.f, a2 = 0.f, a3 = 0.f;
    for (int n = 0; n < CHUNK; n += 4) {
        a0 = fmaf(e[n + 0], vp[(size_t)(n + 0) * Dd], a0);
        a1 = fmaf(e[n + 1], vp[(size_t)(n + 1) * Dd], a1);
        a2 = fmaf(e[n + 2], vp[(size_t)(n + 2) * Dd], a2);
        a3 = fmaf(e[n + 3], vp[(size_t)(n + 3) * Dd], a3);
    }
    part[((size_t)b * NCH + c) * Dd + tid] = ((a0 + a1) + (a2 + a3));
}

__global__ __launch_bounds__(256) void finalize_kernel(
    const float* __restrict__ part, const float* __restrict__ zbuf,
    float* __restrict__ out)
{
    const int b = blockIdx.x;
    const int tid = threadIdx.x;
    float s = 0.f;
#pragma unroll
    for (int c = 0; c < NCH; ++c) s += part[((size_t)b * NCH + c) * Dd + tid];
    out[(size_t)b * Dd + tid] = s / zbuf[b];
}

extern "C" void kernel_launch(void* const* d_in, const int* in_sizes, int n_in,
                              void* d_out, int out_size, void* d_ws, size_t ws_size,
                              hipStream_t stream) {
    const float* Q  = (const float*)d_in[0];
    const float* K  = (const float*)d_in[1];
    const float* V  = (const float*)d_in[2];
    const float* Wq = (const float*)d_in[3];
    const float* Wk = (const float*)d_in[4];
    const float* Wv = (const float*)d_in[5];
    float* out = (float*)d_out;

    // ws layout (bytes): Wf[256K] | scores[512K] | m[128] | z[128] | part[1M]
    char* wsb = (char*)d_ws;
    _Float16* Wf  = (_Float16*)(wsb);
    float* scores = (float*)(wsb + 262144);
    float* mbuf   = (float*)(wsb + 786432);
    float* zbuf   = (float*)(wsb + 786432 + 128);
    float* part   = (float*)(wsb + 786432 + 256);

    prep_w_kernel<<<dim3(64), dim3(256), 0, stream>>>(Wq, Wk, Wf);
    scores_mfma_kernel<<<dim3((Bb * Nn) / 128), dim3(512), 0, stream>>>(Q, K, Wf, Wv, scores);
    softmax_reduce_kernel<<<dim3(Bb), dim3(256), 0, stream>>>(scores, Q, K, Wq, Wk, Wv, mbuf, zbuf, out);
    partial_kernel<<<dim3(NCH, Bb), dim3(256), 0, stream>>>(V, scores, mbuf, part);
    finalize_kernel<<<dim3(Bb), dim3(256), 0, stream>>>(part, zbuf, out);
}